// Round 1
// baseline (3244.063 us; speedup 1.0000x reference)
//
#include <hip/hip_runtime.h>

// KoopmanLQR via structured doubling (SDA): 8 iterations replace 255 Riccati steps.
// Round 4: replace LU + triangular solves with in-place block Gauss-Jordan (sweep)
// inversion of M = I + G*H in ONE 1024-thread kernel (3-level: 16x16 intra-wave
// sweeps -> 64x64 LDS block sweeps -> 256x256 global block sweeps). All solves
// become plain GEMMs. Launches: 119 -> 47. K=256, U=64, BATCH=131072. All fp32.

#define KD 256
#define UD 64
#define NB 131072

// ======================= generic 64x64-tile matmul helper =======================
// C[bi,bj] = op(A)*op(B) (+C0) (+I). All matrices 256x256 row-major ld=256.
__device__ __forceinline__ void mm_tile(const float* __restrict__ Aop,
                                        const float* __restrict__ Bop,
                                        const float* __restrict__ C0,
                                        float* __restrict__ C,
                                        int tra, int trb, int addI, int bi, int bj) {
    __shared__ __align__(16) float At[64 * 68];
    __shared__ __align__(16) float Bt[64 * 68];
    int tid = threadIdx.x;
    int tb = tid >> 4, tj = tid & 15;
    float acc[4][4] = {{0.f}};
    for (int kc = 0; kc < 4; ++kc) {
        __syncthreads();
        if (!tra) {
            for (int e = tid; e < 4096; e += 256) {
                int r = e >> 6, c = e & 63;
                At[c * 68 + r] = Aop[(bi * 64 + r) * 256 + kc * 64 + c];
            }
        } else {
            for (int e = tid; e < 4096; e += 256) {
                int r = e & 63, c = e >> 6;
                At[c * 68 + r] = Aop[(kc * 64 + c) * 256 + bi * 64 + r];
            }
        }
        if (!trb) {
            for (int e = tid; e < 4096; e += 256) {
                int j2 = e & 63, c = e >> 6;
                Bt[c * 68 + j2] = Bop[(kc * 64 + c) * 256 + bj * 64 + j2];
            }
        } else {
            for (int e = tid; e < 4096; e += 256) {
                int j2 = e >> 6, c = e & 63;
                Bt[c * 68 + j2] = Bop[(bj * 64 + j2) * 256 + kc * 64 + c];
            }
        }
        __syncthreads();
        for (int kl = 0; kl < 64; ++kl) {
            float4 a4 = *(const float4*)&At[kl * 68 + 4 * tb];
            float4 b4 = *(const float4*)&Bt[kl * 68 + 4 * tj];
            acc[0][0] += a4.x * b4.x; acc[0][1] += a4.x * b4.y; acc[0][2] += a4.x * b4.z; acc[0][3] += a4.x * b4.w;
            acc[1][0] += a4.y * b4.x; acc[1][1] += a4.y * b4.y; acc[1][2] += a4.y * b4.z; acc[1][3] += a4.y * b4.w;
            acc[2][0] += a4.z * b4.x; acc[2][1] += a4.z * b4.y; acc[2][2] += a4.z * b4.z; acc[2][3] += a4.z * b4.w;
            acc[3][0] += a4.w * b4.x; acc[3][1] += a4.w * b4.y; acc[3][2] += a4.w * b4.z; acc[3][3] += a4.w * b4.w;
        }
    }
    for (int ii = 0; ii < 4; ++ii)
        for (int jj = 0; jj < 4; ++jj) {
            int gi = bi * 64 + 4 * tb + ii, gj = bj * 64 + 4 * tj + jj;
            float vv = acc[ii][jj];
            if (C0) vv += C0[gi * 256 + gj];
            if (addI && gi == gj) vv += 1.f;
            C[gi * 256 + gj] = vv;
        }
}

// ======================= init =======================
__global__ void k_init(const float* __restrict__ ql, const float* __restrict__ rl,
                       const float* __restrict__ gg, const float* __restrict__ A,
                       float* __restrict__ H, float* __restrict__ F,
                       float* __restrict__ a, float* __restrict__ h,
                       float* __restrict__ rinv) {
    int idx = blockIdx.x * 256 + threadIdx.x;
    int i = idx >> 8, j = idx & 255;
    H[idx] = (i == j) ? expf(ql[i]) : 0.f;
    F[idx] = A[idx];
    if (idx < 256) { h[idx] = expf(ql[idx]) * gg[idx]; a[idx] = 0.f; }
    if (idx < 64) rinv[idx] = expf(-rl[idx]);
}

// G = B R^-1 B^T : block per row
__global__ void k_initG(const float* __restrict__ B, const float* __restrict__ rinv,
                        float* __restrict__ G) {
    __shared__ float bi[64];
    int i = blockIdx.x, tid = threadIdx.x;
    if (tid < 64) bi[tid] = B[i * 64 + tid] * rinv[tid];
    __syncthreads();
    float acc = 0.f;
    for (int u = 0; u < 64; ++u) acc += bi[u] * B[tid * 64 + u];
    G[i * 256 + tid] = acc;
}

// ======================= M = I + G*H ; t = a - G*h =======================
__global__ void k_formMt(const float* __restrict__ G, const float* __restrict__ H,
                         const float* __restrict__ a, const float* __restrict__ h,
                         float* __restrict__ M, float* __restrict__ t) {
    if (blockIdx.x < 16) {
        mm_tile(G, H, nullptr, M, 0, 0, 1, (int)blockIdx.x >> 2, (int)blockIdx.x & 3);
    } else {
        int i = threadIdx.x;
        float acc = a[i];
        for (int j = 0; j < 256; ++j) acc -= G[j * 256 + i] * h[j];  // G symmetric
        t[i] = acc;
    }
}

// ======================= in-place block Gauss-Jordan inversion =======================
// M (256x256) -> M^{-1} in place. One workgroup, 1024 threads. Three-level sweep:
//   level 1: 16x16 scalar sweeps, wave 0 only, barrier-free (intra-wave lockstep);
//   level 2: 64x64 block sweep in LDS, rank-16 updates as parallel GEMMs;
//   level 3: 256x256 block sweep over global M, rank-64 updates as float4 GEMMs.
// No pivoting (same stability class as the previous no-pivot LU: M = I + G*H).
// Sweep step J (verified at 2x2 block level, noncommutative-safe ordering):
//   S = inv(A[J][J]); Trow = S*A[J][c];
//   A[r][c] -= A[r][J]*Trow   (r,c != J, reads OLD A[r][J]);
//   A[r][J] = -A[r][J]*S;  A[J][c] = Trow;  A[J][J] = S.
__global__ __launch_bounds__(1024) void k_invert(float* __restrict__ M) {
    __shared__ __align__(16) float W[64 * 68];      // diag block / its inverse S
    __shared__ __align__(16) float Ub[64 * 68];     // one 64x64 operand
    __shared__ __align__(16) float Tr[3][64 * 68];  // S * M[J][cb] row blocks
    __shared__ __align__(16) float T16[16 * 68];    // inv64: S16 * Wrow
    __shared__ __align__(16) float C16[64 * 20];    // inv64: Wcol * S16
    __shared__ __align__(16) float Wd[16 * 20];     // inv16 scratch (bank-spread stride)
    const int tid = threadIdx.x;

    for (int J = 0; J < 4; ++J) {
        // ---- stage diag block into W ----
        __syncthreads();
        for (int e = tid; e < 4096; e += 1024) {
            int r = e >> 6, c = e & 63;
            W[r * 68 + c] = M[(64 * J + r) * 256 + 64 * J + c];
        }
        __syncthreads();

        // ---- invert W in place via 16-wide sweeps ----
        for (int Js = 0; Js < 4; ++Js) {
            // level-1: 16x16 scalar sweep, wave 0, no barriers inside
            if (tid < 64) {
                int r = tid >> 2, s = tid & 3;
                for (int q = 0; q < 4; ++q) {
                    int e = tid * 4 + q, rr = e >> 4, cc = e & 15;
                    Wd[rr * 20 + cc] = W[(16 * Js + rr) * 68 + 16 * Js + cc];
                }
                for (int j = 0; j < 16; ++j) {
                    float piv = Wd[j * 20 + j];
                    float rp = 1.f / piv;
                    float4 pr = *(const float4*)&Wd[j * 20 + 4 * s];
                    float colv = Wd[r * 20 + j];
                    float4 mi = *(const float4*)&Wd[r * 20 + 4 * s];
                    float t0 = pr.x * rp, t1 = pr.y * rp, t2 = pr.z * rp, t3 = pr.w * rp;
                    float m0, m1, m2, m3;
                    if (r == j) { m0 = t0; m1 = t1; m2 = t2; m3 = t3; }
                    else { m0 = mi.x - colv * t0; m1 = mi.y - colv * t1;
                           m2 = mi.z - colv * t2; m3 = mi.w - colv * t3; }
                    if ((j >> 2) == s) {   // fix pivot column element in this chunk
                        float cv = (r == j) ? rp : -colv * rp;
                        int q = j & 3;
                        if (q == 0) m0 = cv; else if (q == 1) m1 = cv;
                        else if (q == 2) m2 = cv; else m3 = cv;
                    }
                    *(float4*)&Wd[r * 20 + 4 * s] = make_float4(m0, m1, m2, m3);
                }
                for (int q = 0; q < 4; ++q) {
                    int e = tid * 4 + q, rr = e >> 4, cc = e & 15;
                    W[(16 * Js + rr) * 68 + 16 * Js + cc] = Wd[rr * 20 + cc];
                }
            }
            __syncthreads();
            // phase a: T16 = S16 * W[Js-rows][*]  (cols in Js-block -> garbage, unused)
            //          C16 = W[*][Js-cols] * S16  (rows in Js-block -> garbage, unused)
            {
                int r = tid >> 6, c = tid & 63;
                float acc = 0.f;
                for (int k = 0; k < 16; ++k)
                    acc += W[(16 * Js + r) * 68 + 16 * Js + k] * W[(16 * Js + k) * 68 + c];
                T16[r * 68 + c] = acc;
                int r2 = tid >> 4, c2 = tid & 15;
                float acc2 = 0.f;
                for (int k = 0; k < 16; ++k)
                    acc2 += W[r2 * 68 + 16 * Js + k] * W[(16 * Js + k) * 68 + 16 * Js + c2];
                C16[r2 * 20 + c2] = acc2;
            }
            __syncthreads();
            // phase b: interior update (reads OLD col Js of W)
            {
                int r = tid >> 4, c4 = (tid & 15) * 4;
                if ((r >> 4) != Js && (c4 >> 4) != Js) {
                    float4 x = *(const float4*)&W[r * 68 + c4];
                    for (int k = 0; k < 16; ++k) {
                        float av = W[r * 68 + 16 * Js + k];
                        const float4 t4 = *(const float4*)&T16[k * 68 + c4];
                        x.x -= av * t4.x; x.y -= av * t4.y; x.z -= av * t4.z; x.w -= av * t4.w;
                    }
                    *(float4*)&W[r * 68 + c4] = x;
                }
            }
            __syncthreads();
            // phase c: write pivot row / pivot column (diag already = S16)
            {
                int r = tid >> 6, c = tid & 63;
                if ((c >> 4) != Js) W[(16 * Js + r) * 68 + c] = T16[r * 68 + c];
                int r2 = tid >> 4, c2 = tid & 15;
                if ((r2 >> 4) != Js) W[r2 * 68 + 16 * Js + c2] = -C16[r2 * 20 + c2];
            }
            __syncthreads();
        }
        // W now holds S = inv(M[J][J])

        // ---- Tr[idx] = S * M[J][cb] for cb != J ----
        int idx = 0;
        for (int cb = 0; cb < 4; ++cb) {
            if (cb == J) continue;
            __syncthreads();
            for (int e = tid; e < 4096; e += 1024) {
                int r = e >> 6, c = e & 63;
                Ub[r * 68 + c] = M[(64 * J + r) * 256 + 64 * cb + c];
            }
            __syncthreads();
            {
                int r = tid >> 4, c4 = (tid & 15) * 4;
                float ax = 0.f, ay = 0.f, az = 0.f, aw = 0.f;
                for (int k = 0; k < 64; ++k) {
                    float av = W[r * 68 + k];
                    const float4 b4 = *(const float4*)&Ub[k * 68 + c4];
                    ax += av * b4.x; ay += av * b4.y; az += av * b4.z; aw += av * b4.w;
                }
                *(float4*)&Tr[idx][r * 68 + c4] = make_float4(ax, ay, az, aw);
            }
            ++idx;
        }

        // ---- per row-block rb != J: interior update + new column block ----
        for (int rb = 0; rb < 4; ++rb) {
            if (rb == J) continue;
            __syncthreads();   // previous rb's GEMMs done reading Ub
            for (int e = tid; e < 4096; e += 1024) {
                int r = e >> 6, c = e & 63;
                Ub[r * 68 + c] = M[(64 * rb + r) * 256 + 64 * J + c];  // OLD col block
            }
            __syncthreads();
            int r = tid >> 4, c4 = (tid & 15) * 4;
            int id2 = 0;
            for (int cb = 0; cb < 4; ++cb) {
                if (cb == J) continue;
                float ax = 0.f, ay = 0.f, az = 0.f, aw = 0.f;
                for (int k = 0; k < 64; ++k) {
                    float av = Ub[r * 68 + k];
                    const float4 b4 = *(const float4*)&Tr[id2][k * 68 + c4];
                    ax += av * b4.x; ay += av * b4.y; az += av * b4.z; aw += av * b4.w;
                }
                float* mp = &M[(64 * rb + r) * 256 + 64 * cb + c4];
                float4 cur = *(const float4*)mp;
                cur.x -= ax; cur.y -= ay; cur.z -= az; cur.w -= aw;
                *(float4*)mp = cur;
                ++id2;
            }
            {   // M[rb][J] = -Ub * S
                float ax = 0.f, ay = 0.f, az = 0.f, aw = 0.f;
                for (int k = 0; k < 64; ++k) {
                    float av = Ub[r * 68 + k];
                    const float4 b4 = *(const float4*)&W[k * 68 + c4];
                    ax += av * b4.x; ay += av * b4.y; az += av * b4.z; aw += av * b4.w;
                }
                *(float4*)&M[(64 * rb + r) * 256 + 64 * J + c4] =
                    make_float4(-ax, -ay, -az, -aw);
            }
        }
        __syncthreads();

        // ---- row J and diag writes ----
        {
            int id3 = 0;
            for (int cb = 0; cb < 4; ++cb) {
                if (cb == J) {
                    for (int e = tid; e < 4096; e += 1024) {
                        int r = e >> 6, c = e & 63;
                        M[(64 * J + r) * 256 + 64 * J + c] = W[r * 68 + c];
                    }
                } else {
                    for (int e = tid; e < 4096; e += 1024) {
                        int r = e >> 6, c = e & 63;
                        M[(64 * J + r) * 256 + 64 * cb + c] = Tr[id3][r * 68 + c];
                    }
                    ++id3;
                }
            }
        }
        __syncthreads();
    }
}

// ======================= apply inverse: XF = M^-1 F, XG = M^-1 G, z = M^-1 t =======================
__global__ __launch_bounds__(256) void k_apply(const float* __restrict__ Minv,
                                               const float* __restrict__ F,
                                               const float* __restrict__ G,
                                               const float* __restrict__ t,
                                               float* __restrict__ XF,
                                               float* __restrict__ XG,
                                               float* __restrict__ z) {
    int b = blockIdx.x;
    if (b < 16)      mm_tile(Minv, F, nullptr, XF, 0, 0, 0, b >> 2, b & 3);
    else if (b < 32) mm_tile(Minv, G, nullptr, XG, 0, 0, 0, (b - 16) >> 2, (b - 16) & 3);
    else {
        __shared__ float ts[256];
        int i = threadIdx.x;
        ts[i] = t[i];
        __syncthreads();
        float acc = 0.f;
        for (int jj = 0; jj < 64; ++jj) {   // per-lane row stream, float4
            const float4 m4 = *(const float4*)&Minv[i * 256 + 4 * jj];
            acc += m4.x * ts[4 * jj] + m4.y * ts[4 * jj + 1]
                 + m4.z * ts[4 * jj + 2] + m4.w * ts[4 * jj + 3];
        }
        z[i] = acc;
    }
}

// ======================= SDA updates =======================
__global__ void k_upd1(const float* __restrict__ F, const float* __restrict__ H,
                       const float* __restrict__ XF, const float* __restrict__ XG,
                       const float* __restrict__ z, const float* __restrict__ h,
                       float* __restrict__ Fn, float* __restrict__ HXF,
                       float* __restrict__ P, float* __restrict__ wv,
                       float* __restrict__ av) {
    int b = blockIdx.x;
    if (b < 16)       mm_tile(F, XF, nullptr, Fn,  0, 0, 0, b >> 2, b & 3);
    else if (b < 32)  mm_tile(H, XF, nullptr, HXF, 0, 0, 0, (b - 16) >> 2, (b - 16) & 3);
    else if (b < 48)  mm_tile(F, XG, nullptr, P,   0, 0, 0, (b - 32) >> 2, (b - 32) & 3);
    else if (b == 48) {
        int i = threadIdx.x;
        float acc = h[i];
        for (int j = 0; j < 256; ++j) acc += H[j * 256 + i] * z[j];  // H symmetric
        wv[i] = acc;
    } else {
        int i = threadIdx.x;
        float acc = 0.f;
        for (int j = 0; j < 256; ++j) acc += F[i * 256 + j] * z[j];
        av[i] = acc;
    }
}

__global__ void k_upd2(const float* __restrict__ F, const float* __restrict__ HXF,
                       const float* __restrict__ P, const float* __restrict__ wv,
                       const float* __restrict__ av, float* __restrict__ H,
                       float* __restrict__ G, float* __restrict__ h,
                       float* __restrict__ a) {
    int b = blockIdx.x;
    if (b < 16)       mm_tile(F, HXF, H, H, 1, 0, 0, b >> 2, b & 3);
    else if (b < 32)  mm_tile(P, F,   G, G, 0, 1, 0, (b - 16) >> 2, (b - 16) & 3);
    else {
        int i = threadIdx.x;
        float acc = h[i];
        for (int pp = 0; pp < 256; ++pp) acc += F[pp * 256 + i] * wv[pp];
        h[i] = acc;
        a[i] += av[i];
    }
}

// ======================= final gains =======================
__global__ void k_btv(const float* __restrict__ B, const float* __restrict__ V,
                      const float* __restrict__ v, float* __restrict__ BtV,
                      float* __restrict__ btv) {
    if (blockIdx.x < 64) {
        int idx = blockIdx.x * 256 + threadIdx.x;
        int i = idx >> 8, q = idx & 255;
        float acc = 0.f;
        for (int p2 = 0; p2 < 256; ++p2) acc += B[p2 * 64 + i] * V[p2 * 256 + q];
        BtV[idx] = acc;
    } else if (threadIdx.x < 64) {
        int i = threadIdx.x;
        float acc = 0.f;
        for (int p2 = 0; p2 < 256; ++p2) acc += B[p2 * 64 + i] * v[p2];
        btv[i] = acc;
    }
}

__global__ void k_SVuu(const float* __restrict__ A, const float* __restrict__ B,
                       const float* __restrict__ rl, const float* __restrict__ BtV,
                       float* __restrict__ S, float* __restrict__ Vuu) {
    int bx = blockIdx.x;
    if (bx < 64) {
        int idx = bx * 256 + threadIdx.x;
        int i = idx >> 8, q = idx & 255;
        float acc = 0.f;
        for (int p2 = 0; p2 < 256; ++p2) acc += BtV[i * 256 + p2] * A[p2 * 256 + q];
        S[idx] = acc;
    } else {
        int tdx = (bx - 64) * 256 + threadIdx.x;
        int i = tdx >> 6, j = tdx & 63;
        float acc = (i == j) ? expf(rl[i]) : 0.f;
        for (int p2 = 0; p2 < 256; ++p2) acc += BtV[i * 256 + p2] * B[p2 * 64 + j];
        Vuu[tdx] = acc;
    }
}

// 64x64 SPD Cholesky, 1 WG
__global__ void k_chol(const float* __restrict__ Vuu, float* __restrict__ L) {
    __shared__ float Msh[64 * 64];
    int tid = threadIdx.x;
    for (int e = tid; e < 4096; e += 256) Msh[e] = Vuu[e];
    __syncthreads();
    int i = tid & 63, c = tid >> 6;
    for (int j = 0; j < 64; ++j) {
        if (tid == 0) Msh[j * 64 + j] = sqrtf(Msh[j * 64 + j]);
        __syncthreads();
        float d = Msh[j * 64 + j];
        if (c == 0 && i > j) Msh[i * 64 + j] /= d;
        __syncthreads();
        if (i > j) {
            float lij = Msh[i * 64 + j];
            for (int k = j + 1 + c; k <= i; k += 4)
                Msh[i * 64 + k] -= lij * Msh[k * 64 + j];
        }
        __syncthreads();
    }
    for (int e = tid; e < 4096; e += 256) {
        int r = e >> 6, k = e & 63;
        L[e] = (k <= r) ? Msh[e] : 0.f;
    }
}

// K0 = Vuu^-1 S, k0 = Vuu^-1 btv (fwd+bwd via wave shuffles)
__global__ void k_solveK(const float* __restrict__ L, const float* __restrict__ S,
                         const float* __restrict__ btv,
                         float* __restrict__ K0, float* __restrict__ k0) {
    int w = (blockIdx.x * 256 + threadIdx.x) >> 6;
    int lane = threadIdx.x & 63;
    if (w >= 257) return;
    float x = (w < 256) ? S[lane * 256 + w] : btv[lane];
    for (int a = 0; a < 64; ++a) {
        float val = (lane < a) ? L[a * 64 + lane] * x : 0.f;
        for (int o = 32; o > 0; o >>= 1) val += __shfl_xor(val, o, 64);
        float xa = (__shfl(x, a, 64) - val) / L[a * 64 + a];
        if (lane == a) x = xa;
    }
    for (int a = 63; a >= 0; --a) {
        float val = (lane > a) ? L[lane * 64 + a] * x : 0.f;
        for (int o = 32; o > 0; o >>= 1) val += __shfl_xor(val, o, 64);
        float xa = (__shfl(x, a, 64) - val) / L[a * 64 + a];
        if (lane == a) x = xa;
    }
    if (w < 256) K0[lane * 256 + w] = x;
    else k0[lane] = x;
}

// u = clip(-g0 @ K0^T + k0)
__global__ __launch_bounds__(256) void k_gemm(const float* __restrict__ g0,
                                              const float* __restrict__ K0,
                                              const float* __restrict__ k0,
                                              float* __restrict__ out) {
    __shared__ __align__(16) float g0t[64 * 68];
    __shared__ __align__(16) float kt[64 * 68];
    int tid = threadIdx.x;
    int base = blockIdx.x * 64;
    int tb = tid >> 4;
    int tj = tid & 15;
    float acc[4][4] = {{0.f}};
    for (int kc = 0; kc < 4; ++kc) {
        __syncthreads();
        for (int e = tid; e < 4096; e += 256) {
            int r = e >> 6, kl = e & 63;
            g0t[kl * 68 + r] = g0[(base + r) * 256 + kc * 64 + kl];
        }
        for (int e = tid; e < 4096; e += 256) {
            int j = e >> 6, kl = e & 63;
            kt[kl * 68 + j] = K0[j * 256 + kc * 64 + kl];
        }
        __syncthreads();
        for (int kl = 0; kl < 64; ++kl) {
            float4 g = *(const float4*)&g0t[kl * 68 + 4 * tb];
            float4 kv = *(const float4*)&kt[kl * 68 + 4 * tj];
            acc[0][0] += g.x * kv.x; acc[0][1] += g.x * kv.y; acc[0][2] += g.x * kv.z; acc[0][3] += g.x * kv.w;
            acc[1][0] += g.y * kv.x; acc[1][1] += g.y * kv.y; acc[1][2] += g.y * kv.z; acc[1][3] += g.y * kv.w;
            acc[2][0] += g.z * kv.x; acc[2][1] += g.z * kv.y; acc[2][2] += g.z * kv.z; acc[2][3] += g.z * kv.w;
            acc[3][0] += g.w * kv.x; acc[3][1] += g.w * kv.y; acc[3][2] += g.w * kv.z; acc[3][3] += g.w * kv.w;
        }
    }
    float c0 = k0[4 * tj + 0], c1 = k0[4 * tj + 1], c2 = k0[4 * tj + 2], c3 = k0[4 * tj + 3];
    for (int i = 0; i < 4; ++i) {
        float4 o;
        o.x = fminf(1.0f, fmaxf(-1.0f, c0 - acc[i][0]));
        o.y = fminf(1.0f, fmaxf(-1.0f, c1 - acc[i][1]));
        o.z = fminf(1.0f, fmaxf(-1.0f, c2 - acc[i][2]));
        o.w = fminf(1.0f, fmaxf(-1.0f, c3 - acc[i][3]));
        *(float4*)&out[(base + 4 * tb + i) * 64 + 4 * tj] = o;
    }
}

extern "C" void kernel_launch(void* const* d_in, const int* in_sizes, int n_in,
                              void* d_out, int out_size, void* d_ws, size_t ws_size,
                              hipStream_t stream) {
    const float* g0 = (const float*)d_in[0];
    const float* A  = (const float*)d_in[1];
    const float* B  = (const float*)d_in[2];
    const float* ql = (const float*)d_in[3];
    const float* rl = (const float*)d_in[4];
    const float* gg = (const float*)d_in[5];
    // d_in[6] = T == 256, hardcoded (log2 T = 8 doublings).

    float* ws = (float*)d_ws;
    float* G    = ws;             // 65536
    float* H    = G    + 65536;
    float* F0   = H    + 65536;
    float* F1   = F0   + 65536;
    float* M    = F1   + 65536;
    float* XF   = M    + 65536;
    float* XG   = XF   + 65536;
    float* HXF  = XG   + 65536;
    float* P    = HXF  + 65536;
    float* BtV  = P    + 65536;   // 16384
    float* S    = BtV  + 16384;   // 16384
    float* K0   = S    + 16384;   // 16384
    float* Vuu  = K0   + 16384;   // 4096
    float* L64  = Vuu  + 4096;    // 4096
    float* a    = L64  + 4096;    // 256
    float* h    = a    + 256;     // 256
    float* t    = h    + 256;     // 256
    float* z    = t    + 256;     // 256
    float* wv   = z    + 256;     // 256
    float* av   = wv   + 256;     // 256
    float* rinv = av   + 256;     // 64
    float* btv  = rinv + 64;      // 64
    float* k0v  = btv  + 64;      // 64

    k_init<<<256, 256, 0, stream>>>(ql, rl, gg, A, H, F0, a, h, rinv);
    k_initG<<<256, 256, 0, stream>>>(B, rinv, G);

    float* Fc = F0; float* Fn = F1;
    for (int it = 0; it < 8; ++it) {
        k_formMt<<<17, 256, 0, stream>>>(G, H, a, h, M, t);
        k_invert<<<1, 1024, 0, stream>>>(M);                       // M -> M^{-1} in place
        k_apply<<<33, 256, 0, stream>>>(M, Fc, G, t, XF, XG, z);   // pure GEMM solves
        k_upd1<<<50, 256, 0, stream>>>(Fc, H, XF, XG, z, h, Fn, HXF, P, wv, av);
        k_upd2<<<33, 256, 0, stream>>>(Fc, HXF, P, wv, av, H, G, h, a);
        float* tmp = Fc; Fc = Fn; Fn = tmp;
    }

    // gains from V = H_8, v = h_8
    k_btv<<<65, 256, 0, stream>>>(B, H, h, BtV, btv);
    k_SVuu<<<80, 256, 0, stream>>>(A, B, rl, BtV, S, Vuu);
    k_chol<<<1, 256, 0, stream>>>(Vuu, L64);
    k_solveK<<<65, 256, 0, stream>>>(L64, S, btv, K0, k0v);
    k_gemm<<<NB / 64, 256, 0, stream>>>(g0, K0, k0v, (float*)d_out);
}